// Round 2
// baseline (385.268 us; speedup 1.0000x reference)
//
#include <hip/hip_runtime.h>
#include <hip/hip_bf16.h>

#define N_G   2048
#define IMGF  128.0f
#define RECF  9          // floats per gaussian record

// record layout: [0]=mu_x [1]=mu_y [2]=A2 (dx^2 coeff) [3]=B2 (dx*dy coeff)
// [4]=D2 (dy^2 coeff) [5]=L (log2(op), -1e10 if invalid) [6..8]=rgb
// p2 = A2*dx^2 + B2*dx*dy + D2*dy^2 + L ;  alpha = min(exp2(p2), 0.99)

__global__ void gs_preprocess(const float* __restrict__ means,
                              const float* __restrict__ log_scales,
                              const float* __restrict__ rotations,
                              const float* __restrict__ opacity_logit,
                              const float* __restrict__ color_pre,
                              const float* __restrict__ cam_pos,
                              const float* __restrict__ look_at,
                              float* __restrict__ rec,
                              float* __restrict__ depth)
{
    int i = blockIdx.x * blockDim.x + threadIdx.x;
    if (i >= N_G) return;

    // ---- camera basis (uniform, cheap to recompute per thread) ----
    float cx = cam_pos[0], cy = cam_pos[1], cz = cam_pos[2];
    float fx = look_at[0] - cx, fy = look_at[1] - cy, fz = look_at[2] - cz;
    float fn = 1.0f / sqrtf(fx*fx + fy*fy + fz*fz);
    fx *= fn; fy *= fn; fz *= fn;
    // right = cross(fwd, (0,1,0)) = (-fz, 0, fx)
    float rx = -fz, ry = 0.0f, rz = fx;
    float rn = 1.0f / sqrtf(rx*rx + ry*ry + rz*rz);
    rx *= rn; ry *= rn; rz *= rn;
    // up = cross(right, fwd)
    float ux = ry*fz - rz*fy, uy = rz*fx - rx*fz, uz = rx*fy - ry*fx;

    // ---- project mean ----
    float mx = means[3*i+0] - cx, my = means[3*i+1] - cy, mz = means[3*i+2] - cz;
    float m0 =  rx*mx + ry*my + rz*mz;
    float m1 =  ux*mx + uy*my + uz*mz;
    float m2 = -(fx*mx + fy*my + fz*mz);
    float d  = -m2;
    float invz = 1.0f / (-m2 + 1e-8f);
    float m2dx =  (m0 * invz) * IMGF + IMGF * 0.5f;
    float m2dy = -(m1 * invz) * IMGF + IMGF * 0.5f;

    // ---- cov3d = R diag(s^2) R^T ----
    float s0 = expf(log_scales[3*i+0]);
    float s1 = expf(log_scales[3*i+1]);
    float s2 = expf(log_scales[3*i+2]);
    float qw = rotations[4*i+0], qx = rotations[4*i+1],
          qy = rotations[4*i+2], qz = rotations[4*i+3];
    float qn = 1.0f / sqrtf(qw*qw + qx*qx + qy*qy + qz*qz);
    qw *= qn; qx *= qn; qy *= qn; qz *= qn;
    float R00 = 1-2*(qy*qy+qz*qz), R01 = 2*(qx*qy-qw*qz), R02 = 2*(qx*qz+qw*qy);
    float R10 = 2*(qx*qy+qw*qz), R11 = 1-2*(qx*qx+qz*qz), R12 = 2*(qy*qz-qw*qx);
    float R20 = 2*(qx*qz-qw*qy), R21 = 2*(qy*qz+qw*qx), R22 = 1-2*(qx*qx+qy*qy);
    float t0 = s0*s0, t1 = s1*s1, t2 = s2*s2;
    float C00 = R00*R00*t0 + R01*R01*t1 + R02*R02*t2;
    float C01 = R00*R10*t0 + R01*R11*t1 + R02*R12*t2;
    float C02 = R00*R20*t0 + R01*R21*t1 + R02*R22*t2;
    float C11 = R10*R10*t0 + R11*R11*t1 + R12*R12*t2;
    float C12 = R10*R20*t0 + R11*R21*t1 + R12*R22*t2;
    float C22 = R20*R20*t0 + R21*R21*t1 + R22*R22*t2;

    // ---- cov_cam 2x2 (rows: right, up) ----
    float v0 = C00*rx + C01*ry + C02*rz;
    float v1 = C01*rx + C11*ry + C12*rz;
    float v2 = C02*rx + C12*ry + C22*rz;
    float ca = rx*v0 + ry*v1 + rz*v2;          // [0,0]
    float cb = ux*v0 + uy*v1 + uz*v2;          // [0,1]
    float w0 = C00*ux + C01*uy + C02*uz;
    float w1 = C01*ux + C11*uy + C12*uz;
    float w2 = C02*ux + C12*uy + C22*uz;
    float cd = ux*w0 + uy*w1 + uz*w2;          // [1,1]

    float z2 = fmaxf(d*d, 0.01f);
    float sc = (IMGF * IMGF) / z2;
    float a  = ca*sc + 0.3f;
    float b  = cb*sc;
    float dd = cd*sc + 0.3f;
    float det  = fmaxf(a*dd - b*b, 1e-6f);
    float idet = 1.0f / det;

    bool valid = (d > 0.1f) && (m2dx > -IMGF) && (m2dx < 2.0f*IMGF)
                            && (m2dy > -IMGF) && (m2dy < 2.0f*IMGF);

    float op = 1.0f / (1.0f + expf(-opacity_logit[i]));
    const float L2E = 1.4426950408889634f;
    float A2 = -0.5f * L2E * dd * idet;
    float B2 =          L2E * b  * idet;   // -0.5 * (-2b/det)
    float D2 = -0.5f * L2E * a  * idet;
    float L  = valid ? log2f(op) : -1e10f;

    float cr = 1.0f / (1.0f + expf(-color_pre[3*i+0]));
    float cg = 1.0f / (1.0f + expf(-color_pre[3*i+1]));
    float cl = 1.0f / (1.0f + expf(-color_pre[3*i+2]));

    float* r9 = rec + RECF*i;
    r9[0] = m2dx; r9[1] = m2dy; r9[2] = A2; r9[3] = B2; r9[4] = D2;
    r9[5] = L;    r9[6] = cr;   r9[7] = cg; r9[8] = cl;
    depth[i] = d;
}

// 1 block x 1024 threads: bitonic sort of 2048 (depth, idx) pairs in LDS,
// tiebreak on idx == stable argsort; then gather records into sorted order.
__global__ void __launch_bounds__(1024)
gs_sort_gather(const float* __restrict__ depth,
               const float* __restrict__ rec,
               float* __restrict__ srec)
{
    __shared__ float k_[N_G];
    __shared__ int   v_[N_G];
    int t = threadIdx.x;
    k_[t]        = depth[t];        v_[t]        = t;
    k_[t + 1024] = depth[t + 1024]; v_[t + 1024] = t + 1024;
    __syncthreads();

    for (int k = 2; k <= N_G; k <<= 1) {
        for (int j = k >> 1; j > 0; j >>= 1) {
            int i = (t & (j - 1)) | ((t & ~(j - 1)) << 1);
            int l = i | j;
            float ki = k_[i], kl = k_[l];
            int   vi = v_[i], vl = v_[l];
            bool asc = ((i & k) == 0);
            bool sw = asc ? (ki > kl || (ki == kl && vi > vl))
                          : (ki < kl || (ki == kl && vi < vl));
            if (sw) { k_[i] = kl; k_[l] = ki; v_[i] = vl; v_[l] = vi; }
            __syncthreads();
        }
    }

    for (int e = t; e < N_G; e += 1024) {
        int src = v_[e];
        const float* s = rec + RECF * src;
        float*       o = srec + RECF * e;
        #pragma unroll
        for (int q = 0; q < RECF; ++q) o[q] = s[q];
    }
}

// one thread per pixel; LDS-staged chunks of 256 sorted gaussians
__global__ void __launch_bounds__(256)
gs_raster(const float* __restrict__ srec, float* __restrict__ out)
{
    __shared__ float s_rec[256 * RECF];
    int t = threadIdx.x;
    int p = blockIdx.x * 256 + t;
    float px = (float)(p & 127);
    float py = (float)(p >> 7);

    float Ir = 1.0f, Ig = 1.0f, Ib = 1.0f, T = 1.0f;
    bool done = false;

    for (int base = 0; base < N_G; base += 256) {
        // barrier doubles as block-wide early-out vote
        int cnt = __syncthreads_count(done ? 1 : 0);
        if (cnt == 256) break;

        const float* g = srec + base * RECF;
        for (int q = t; q < 256 * RECF; q += 256) s_rec[q] = g[q];
        __syncthreads();

        if (!done) {
            for (int j = 0; j < 256; ++j) {
                const float* r = s_rec + j * RECF;
                float dx = px - r[0];
                float dy = py - r[1];
                // p2 = A2*dx^2 + B2*dx*dy + D2*dy^2 + L
                float p2 = fmaf(dx, fmaf(r[2], dx, r[3] * dy),
                                fmaf(r[4] * dy, dy, r[5]));
                if (p2 > -25.0f) {          // alpha < 3e-8 -> skip
                    float alpha = fminf(exp2f(p2), 0.99f);
                    float w = T * alpha;
                    Ir = fmaf(w, r[6] - Ir, Ir);
                    Ig = fmaf(w, r[7] - Ig, Ig);
                    Ib = fmaf(w, r[8] - Ib, Ib);
                    T -= w;                 // T *= (1 - alpha)
                    if (T < 1e-4f) { done = true; break; }
                }
            }
        }
    }

    float* o = out + p * 3;
    o[0] = fminf(fmaxf(Ir, 0.0f), 1.0f);
    o[1] = fminf(fmaxf(Ig, 0.0f), 1.0f);
    o[2] = fminf(fmaxf(Ib, 0.0f), 1.0f);
}

extern "C" void kernel_launch(void* const* d_in, const int* in_sizes, int n_in,
                              void* d_out, int out_size, void* d_ws, size_t ws_size,
                              hipStream_t stream)
{
    const float* means         = (const float*)d_in[0];
    const float* log_scales    = (const float*)d_in[1];
    const float* rotations     = (const float*)d_in[2];
    const float* opacity_logit = (const float*)d_in[3];
    const float* color_pre     = (const float*)d_in[4];
    const float* cam_pos       = (const float*)d_in[5];
    const float* look_at       = (const float*)d_in[6];
    float* out = (float*)d_out;

    char* ws = (char*)d_ws;
    float* rec   = (float*)(ws);                                   // 2048*9 f
    float* depth = (float*)(ws + N_G * RECF * 4);                  // 2048 f
    float* srec  = (float*)(ws + N_G * RECF * 4 + N_G * 4);        // 2048*9 f

    hipLaunchKernelGGL(gs_preprocess, dim3(N_G / 256), dim3(256), 0, stream,
                       means, log_scales, rotations, opacity_logit, color_pre,
                       cam_pos, look_at, rec, depth);
    hipLaunchKernelGGL(gs_sort_gather, dim3(1), dim3(1024), 0, stream,
                       depth, rec, srec);
    hipLaunchKernelGGL(gs_raster, dim3(16384 / 256), dim3(256), 0, stream,
                       srec, out);
}

// Round 3
// 271.292 us; speedup vs baseline: 1.4201x; 1.4201x over previous
//
#include <hip/hip_runtime.h>
#include <hip/hip_bf16.h>

#define N_G   2048
#define IMGF  128.0f
#define RECF  12         // floats per gaussian record (3 x float4)

// record layout (3 float4):
//  r4[0] = {mu_x, mu_y, A2, B2}
//  r4[1] = {D2,   L,    cr, cg}
//  r4[2] = {cb,   0,    0,  0 }
// p2 = A2*dx^2 + B2*dx*dy + D2*dy^2 + L ;  alpha = min(exp2(p2), 0.99)
// L = log2(opacity) or -1e10 if invalid (exp2 -> 0 reproduces valid-mask)

__global__ void gs_preprocess(const float* __restrict__ means,
                              const float* __restrict__ log_scales,
                              const float* __restrict__ rotations,
                              const float* __restrict__ opacity_logit,
                              const float* __restrict__ color_pre,
                              const float* __restrict__ cam_pos,
                              const float* __restrict__ look_at,
                              float* __restrict__ rec,
                              float* __restrict__ depth)
{
    int i = blockIdx.x * blockDim.x + threadIdx.x;
    if (i >= N_G) return;

    // ---- camera basis (uniform, cheap to recompute per thread) ----
    float cx = cam_pos[0], cy = cam_pos[1], cz = cam_pos[2];
    float fx = look_at[0] - cx, fy = look_at[1] - cy, fz = look_at[2] - cz;
    float fn = 1.0f / sqrtf(fx*fx + fy*fy + fz*fz);
    fx *= fn; fy *= fn; fz *= fn;
    float rx = -fz, ry = 0.0f, rz = fx;                 // cross(fwd,(0,1,0))
    float rn = 1.0f / sqrtf(rx*rx + ry*ry + rz*rz);
    rx *= rn; ry *= rn; rz *= rn;
    float ux = ry*fz - rz*fy, uy = rz*fx - rx*fz, uz = rx*fy - ry*fx;

    // ---- project mean ----
    float mx = means[3*i+0] - cx, my = means[3*i+1] - cy, mz = means[3*i+2] - cz;
    float m0 =  rx*mx + ry*my + rz*mz;
    float m1 =  ux*mx + uy*my + uz*mz;
    float m2 = -(fx*mx + fy*my + fz*mz);
    float d  = -m2;
    float invz = 1.0f / (-m2 + 1e-8f);
    float m2dx =  (m0 * invz) * IMGF + IMGF * 0.5f;
    float m2dy = -(m1 * invz) * IMGF + IMGF * 0.5f;

    // ---- cov3d = R diag(s^2) R^T ----
    float s0 = expf(log_scales[3*i+0]);
    float s1 = expf(log_scales[3*i+1]);
    float s2 = expf(log_scales[3*i+2]);
    float qw = rotations[4*i+0], qx = rotations[4*i+1],
          qy = rotations[4*i+2], qz = rotations[4*i+3];
    float qn = 1.0f / sqrtf(qw*qw + qx*qx + qy*qy + qz*qz);
    qw *= qn; qx *= qn; qy *= qn; qz *= qn;
    float R00 = 1-2*(qy*qy+qz*qz), R01 = 2*(qx*qy-qw*qz), R02 = 2*(qx*qz+qw*qy);
    float R10 = 2*(qx*qy+qw*qz), R11 = 1-2*(qx*qx+qz*qz), R12 = 2*(qy*qz-qw*qx);
    float R20 = 2*(qx*qz-qw*qy), R21 = 2*(qy*qz+qw*qx), R22 = 1-2*(qx*qx+qy*qy);
    float t0 = s0*s0, t1 = s1*s1, t2 = s2*s2;
    float C00 = R00*R00*t0 + R01*R01*t1 + R02*R02*t2;
    float C01 = R00*R10*t0 + R01*R11*t1 + R02*R12*t2;
    float C02 = R00*R20*t0 + R01*R21*t1 + R02*R22*t2;
    float C11 = R10*R10*t0 + R11*R11*t1 + R12*R12*t2;
    float C12 = R10*R20*t0 + R11*R21*t1 + R12*R22*t2;
    float C22 = R20*R20*t0 + R21*R21*t1 + R22*R22*t2;

    // ---- cov_cam 2x2 (rows: right, up) ----
    float v0 = C00*rx + C01*ry + C02*rz;
    float v1 = C01*rx + C11*ry + C12*rz;
    float v2 = C02*rx + C12*ry + C22*rz;
    float ca = rx*v0 + ry*v1 + rz*v2;
    float cb = ux*v0 + uy*v1 + uz*v2;
    float w0 = C00*ux + C01*uy + C02*uz;
    float w1 = C01*ux + C11*uy + C12*uz;
    float w2 = C02*ux + C12*uy + C22*uz;
    float cd = ux*w0 + uy*w1 + uz*w2;

    float z2 = fmaxf(d*d, 0.01f);
    float sc = (IMGF * IMGF) / z2;
    float a  = ca*sc + 0.3f;
    float b  = cb*sc;
    float dd = cd*sc + 0.3f;
    float det  = fmaxf(a*dd - b*b, 1e-6f);
    float idet = 1.0f / det;

    bool valid = (d > 0.1f) && (m2dx > -IMGF) && (m2dx < 2.0f*IMGF)
                            && (m2dy > -IMGF) && (m2dy < 2.0f*IMGF);

    float op = 1.0f / (1.0f + expf(-opacity_logit[i]));
    const float L2E = 1.4426950408889634f;
    float A2 = -0.5f * L2E * dd * idet;
    float B2 =          L2E * b  * idet;
    float D2 = -0.5f * L2E * a  * idet;
    float L  = valid ? log2f(op) : -1e10f;

    float cr = 1.0f / (1.0f + expf(-color_pre[3*i+0]));
    float cg = 1.0f / (1.0f + expf(-color_pre[3*i+1]));
    float cl = 1.0f / (1.0f + expf(-color_pre[3*i+2]));

    float4* r4 = (float4*)(rec + RECF*i);
    r4[0] = make_float4(m2dx, m2dy, A2, B2);
    r4[1] = make_float4(D2, L, cr, cg);
    r4[2] = make_float4(cl, 0.0f, 0.0f, 0.0f);
    depth[i] = d;
}

// O(N^2) stable rank sort: thread i counts #{j: d_j < d_i || (d_j==d_i && j<i)},
// then scatters its (padded) record to srec[rank]. 32 blocks x 64, no barriers.
__global__ void __launch_bounds__(64)
gs_rank_scatter(const float* __restrict__ depth,
                const float* __restrict__ rec,
                float* __restrict__ srec)
{
    int i = blockIdx.x * 64 + threadIdx.x;
    float di = depth[i];
    int rank = 0;
    for (int j = 0; j < N_G; j += 4) {
        float4 dj = *(const float4*)(depth + j);
        rank += (dj.x < di) || (dj.x == di && (j+0) < i);
        rank += (dj.y < di) || (dj.y == di && (j+1) < i);
        rank += (dj.z < di) || (dj.z == di && (j+2) < i);
        rank += (dj.w < di) || (dj.w == di && (j+3) < i);
    }
    const float4* s = (const float4*)(rec + RECF*i);
    float4*       o = (float4*)(srec + RECF*rank);
    o[0] = s[0]; o[1] = s[1]; o[2] = s[2];
}

// one thread per pixel; 256 blocks x 64 threads -> 1 wave/CU (no LDS sharing).
// Branchless unrolled inner loop; wave-uniform early exit every 32 gaussians.
__global__ void __launch_bounds__(64)
gs_raster(const float* __restrict__ srec, float* __restrict__ out)
{
    __shared__ float4 s_rec[256 * 3];
    int t = threadIdx.x;
    int p = blockIdx.x * 64 + t;
    float px = (float)(p & 127);
    float py = (float)(p >> 7);

    float Ir = 1.0f, Ig = 1.0f, Ib = 1.0f, T = 1.0f;
    bool done = false;

    for (int base = 0; base < N_G; base += 256) {
        // stage 256 gaussians (12 KB) -> LDS, coalesced
        const float4* g4 = (const float4*)(srec + base * RECF);
        #pragma unroll
        for (int q = 0; q < 12; ++q) s_rec[t + q*64] = g4[t + q*64];
        __syncthreads();

        for (int jb = 0; jb < 256; jb += 32) {
            #pragma unroll
            for (int j = jb; j < jb + 32; ++j) {
                float4 ra = s_rec[j*3+0];
                float4 rb = s_rec[j*3+1];
                float4 rc = s_rec[j*3+2];
                float dx = px - ra.x;
                float dy = py - ra.y;
                float p2 = fmaf(dx, fmaf(ra.z, dx, ra.w * dy),
                                fmaf(rb.x * dy, dy, rb.y));
                float al = fminf(__builtin_amdgcn_exp2f(p2), 0.99f);
                float w  = T * al;                 // serial chain: 2 ops/iter
                Ir = fmaf(w, rb.z - Ir, Ir);
                Ig = fmaf(w, rb.w - Ig, Ig);
                Ib = fmaf(w, rc.x - Ib, Ib);
                T -= w;
            }
            if (__all(T < 1e-4f)) { done = true; break; }
        }
        __syncthreads();
        if (done) break;
    }

    float* o = out + p * 3;
    o[0] = fminf(fmaxf(Ir, 0.0f), 1.0f);
    o[1] = fminf(fmaxf(Ig, 0.0f), 1.0f);
    o[2] = fminf(fmaxf(Ib, 0.0f), 1.0f);
}

extern "C" void kernel_launch(void* const* d_in, const int* in_sizes, int n_in,
                              void* d_out, int out_size, void* d_ws, size_t ws_size,
                              hipStream_t stream)
{
    const float* means         = (const float*)d_in[0];
    const float* log_scales    = (const float*)d_in[1];
    const float* rotations     = (const float*)d_in[2];
    const float* opacity_logit = (const float*)d_in[3];
    const float* color_pre     = (const float*)d_in[4];
    const float* cam_pos       = (const float*)d_in[5];
    const float* look_at       = (const float*)d_in[6];
    float* out = (float*)d_out;

    char* ws = (char*)d_ws;
    float* rec   = (float*)(ws);                                     // 2048*12 f
    float* depth = (float*)(ws + N_G * RECF * 4);                    // 2048 f
    float* srec  = (float*)(ws + N_G * RECF * 4 + N_G * 4);          // 2048*12 f

    hipLaunchKernelGGL(gs_preprocess, dim3(N_G / 256), dim3(256), 0, stream,
                       means, log_scales, rotations, opacity_logit, color_pre,
                       cam_pos, look_at, rec, depth);
    hipLaunchKernelGGL(gs_rank_scatter, dim3(N_G / 64), dim3(64), 0, stream,
                       depth, rec, srec);
    hipLaunchKernelGGL(gs_raster, dim3(16384 / 64), dim3(64), 0, stream,
                       srec, out);
}